// Round 7
// baseline (389.587 us; speedup 1.0000x reference)
//
#include <hip/hip_runtime.h>

constexpr int DEG = 31;        // neighbors per node
constexpr int NEV = 32;        // events per node (self + neighbors)
constexpr int TH  = 16;        // threshold: dp[0..15] + absorbing "over"
constexpr int BLK = 256;       // fallback block size
constexpr int TBL = 1 << 20;   // u8 table entries (padded >= n)

// fused kernel geometry
constexpr int CH    = 1 << 16;   // 64 KB LDS chunk
constexpr int NPASS = TBL / CH;  // 16 passes per half
constexpr int BLKF  = 1024;      // 16 waves: 8 scan + 8 direct
constexpr int NPB   = 2048;      // nodes per fused block (1024 scan + 1024 direct)

typedef int  vint4  __attribute__((ext_vector_type(4)));

__global__ void zero_out_kernel(float* out) {
    if (threadIdx.x == 0) out[0] = 0.0f;
}

__device__ __forceinline__ float fast_sigmoid(float x) {
    return 1.0f / (1.0f + __expf(-x));
}

// raw barrier: HW rendezvous WITHOUT the vmcnt(0) drain __syncthreads implies.
__device__ __forceinline__ void barrier_raw() {
    asm volatile("" ::: "memory");
    __builtin_amdgcn_s_barrier();
    asm volatile("" ::: "memory");
}

// ---- phase 1: u8 table tbl[i] = rint(sigmoid(gains[i])*255) + zero out ----
__global__ __launch_bounds__(256)
void build_table_kernel(const float* __restrict__ gains,
                        unsigned* __restrict__ tbl4,
                        float* __restrict__ out, int n) {
    const int t = blockIdx.x * 256 + threadIdx.x;
    if (t == 0) out[0] = 0.0f;
    if (t < TBL / 4) {
        unsigned w = 0;
        #pragma unroll
        for (int k = 0; k < 4; ++k) {
            const int i = 4 * t + k;
            const float p = (i < n) ? fast_sigmoid(gains[i]) : 0.0f;
            const unsigned b = __float2uint_rn(p * 255.0f);
            w |= (b & 0xFFu) << (8 * k);
        }
        tbl4[t] = w;
    }
}

// Poisson-binomial DP from packed u8 probability bytes (original j-order ->
// bit-identical per-node result vs all previous passing kernels).
__device__ __forceinline__ float node_dp(float g, const unsigned w[8]) {
    const float p0 = fast_sigmoid(g);
    float dp[TH];
    dp[0] = 1.0f;
    #pragma unroll
    for (int k = 1; k < TH; ++k) dp[k] = 0.0f;
    float over = 0.0f;
    #pragma unroll
    for (int j = 0; j < NEV; ++j) {
        float pj;
        if (j == 0) {
            pj = p0;
        } else {
            const unsigned b = (w[(j - 1) >> 2] >> (((j - 1) & 3) * 8)) & 0xFFu;
            pj = (float)b * (1.0f / 255.0f);
        }
        if (j >= TH - 1) over = fmaf(dp[TH - 1], pj, over);
        const int kmax = (j + 1 < TH - 1) ? (j + 1) : (TH - 1);
        #pragma unroll
        for (int k = kmax; k >= 1; --k)
            dp[k] = fmaf(pj, dp[k - 1] - dp[k], dp[k]);
        dp[0] = fmaf(-pj, dp[0], dp[0]);
    }
    return fmaf(0.25f, p0, -over);
}

// ---- fused wave-specialized kernel ----
// Waves 0-7: SCAN role (LDS chunk passes). Waves 8-15: DIRECT role — 31 plain
// C++ byte loads issued before the pass loop, consumed after it. The compiler
// inserts s_waitcnt only before first use (G7), and loads can't cross the
// barrier_raw asm memory clobbers, so they stay in flight across all raw
// barriers with compiler-guaranteed correctness (r6's inline-asm version read
// pending-load dest regs via compiler copies -> stale data).
__global__ __launch_bounds__(BLKF, 4)
void pgl_fused_kernel(const float* __restrict__ gains,
                      const int*   __restrict__ nbr,
                      const unsigned char* __restrict__ tbl,
                      float*       __restrict__ out, int n) {
    __shared__ __align__(16) unsigned char smem[CH];   // 64 KB multi-purpose

    const int  tid      = threadIdx.x;
    const bool scanRole = (tid < 512);                 // wave-uniform split
    const int  blockStart = blockIdx.x * NPB;

    float local = 0.0f;

    #pragma unroll 1
    for (int half = 0; half < 2; ++half) {
        // ---- bounce: fill this half's 31 indices (scan rows, then direct rows)
        unsigned idx[DEG];
        #pragma unroll 1
        for (int rnd = 0; rnd < 2; ++rnd) {
            const int rowBase = blockStart + rnd * 1024 + half * 512;
            const int rowsR   = min(512, max(0, n - rowBase));
            const int elems   = rowsR * DEG;
            __syncthreads();                           // smem free; full drain ok here
            {
                const vint4* nb4 = (const vint4*)(nbr + (size_t)rowBase * DEG);
                vint4* s4 = (vint4*)smem;
                const int nvec = elems >> 2;
                for (int v = tid; v < nvec; v += BLKF)
                    s4[v] = __builtin_nontemporal_load(nb4 + v);
                for (int e = (nvec << 2) + tid; e < elems; e += BLKF)
                    ((int*)smem)[e] = __builtin_nontemporal_load(nbr + (size_t)rowBase * DEG + e);
            }
            __syncthreads();
            const bool myRound = (rnd == 0) ? scanRole : !scanRole;
            if (myRound) {
                const int s = scanRole ? tid : (tid - 512);
                if (s < rowsR) {
                    const int* row = (const int*)smem + s * DEG;
                    #pragma unroll
                    for (int j = 0; j < DEG; ++j) idx[j] = (unsigned)row[j];
                } else {
                    #pragma unroll
                    for (int j = 0; j < DEG; ++j) idx[j] = 0u;
                }
            }
        }

        unsigned w[8];
        #pragma unroll
        for (int q = 0; q < 8; ++q) w[q] = 0u;

        // ---- direct role: issue all 31 gathers NOW (plain loads, no use yet)
        unsigned gb[DEG];
        if (!scanRole) {
            #pragma unroll
            for (int j = 0; j < DEG; ++j) gb[j] = (unsigned)tbl[idx[j]];
        }
        __builtin_amdgcn_sched_barrier(0);   // pin: no sinking into the pass loop

        // ---- pass loop: raw barriers only (direct waves' loads stay in flight)
        #pragma unroll 1
        for (int c = 0; c < NPASS; ++c) {
            barrier_raw();                             // (A) prev chunk consumed
            if (scanRole) {
                // stage 64 KB chunk: 512 threads x 128 B
                const vint4* src = (const vint4*)(tbl + (size_t)c * CH);
                vint4* dst = (vint4*)smem;
                vint4 t0 = src[0 * 512 + tid], t1 = src[1 * 512 + tid],
                      t2 = src[2 * 512 + tid], t3 = src[3 * 512 + tid];
                dst[0 * 512 + tid] = t0; dst[1 * 512 + tid] = t1;
                dst[2 * 512 + tid] = t2; dst[3 * 512 + tid] = t3;
                t0 = src[4 * 512 + tid]; t1 = src[5 * 512 + tid];
                t2 = src[6 * 512 + tid]; t3 = src[7 * 512 + tid];
                dst[4 * 512 + tid] = t0; dst[5 * 512 + tid] = t1;
                dst[6 * 512 + tid] = t2; dst[7 * 512 + tid] = t3;
                asm volatile("s_waitcnt lgkmcnt(0)" ::: "memory");
            }
            barrier_raw();                             // (B) chunk c ready
            if (scanRole) {
                const unsigned cbase = (unsigned)c * (unsigned)CH;
                #pragma unroll
                for (int j = 0; j < DEG; ++j) {
                    const unsigned r = idx[j] - cbase;   // unsigned wrap = chunk test
                    if (r < (unsigned)CH)
                        w[j >> 2] |= (unsigned)smem[r] << ((j & 3) * 8);
                }
            }
        }

        // ---- direct role: consume gathers (compiler emits the waitcnt here)
        if (!scanRole) {
            #pragma unroll
            for (int j = 0; j < DEG; ++j)
                w[j >> 2] |= (gb[j] & 0xFFu) << ((j & 3) * 8);
        }

        // ---- DP for this half's node ----
        const int node = blockStart + half * 512 + tid + (scanRole ? 0 : 512);
        if (node < n)
            local += node_dp(__builtin_nontemporal_load(gains + node), w);
    }

    // ---- block reduction ----
    #pragma unroll
    for (int o = 32; o > 0; o >>= 1) local += __shfl_down(local, o, 64);
    __syncthreads();                                   // all loads consumed by now
    if ((tid & 63) == 0) ((float*)smem)[tid >> 6] = local;
    __syncthreads();
    if (tid == 0) {
        float s = 0.0f;
        #pragma unroll
        for (int wv = 0; wv < BLKF / 64; ++wv) s += ((float*)smem)[wv];
        atomicAdd(out, s);
    }
}

// ---- fallback (ws too small): f32 direct gather ----
__global__ __launch_bounds__(BLK)
void pgl_direct_kernel(const float* __restrict__ gains,
                       const int*   __restrict__ nbr,
                       float*       __restrict__ out, int n) {
    __shared__ int s_idx[BLK * DEG];
    __shared__ float s_red[BLK / 64];
    const int tid = threadIdx.x;
    const int blockStart = blockIdx.x * BLK;
    const int rows  = min(BLK, n - blockStart);
    const int elems = rows * DEG;
    const int base  = blockStart * DEG;
    const int4* nb4 = (const int4*)(nbr + base);
    int4* s4 = (int4*)s_idx;
    const int nvec = elems >> 2;
    for (int v = tid; v < nvec; v += BLK) s4[v] = nb4[v];
    for (int e = (nvec << 2) + tid; e < elems; e += BLK) s_idx[e] = nbr[base + e];
    __syncthreads();
    float local = 0.0f;
    const int i = blockStart + tid;
    if (i < n) {
        const int* row = s_idx + tid * DEG;
        float dp[TH];
        dp[0] = 1.0f;
        #pragma unroll
        for (int k = 1; k < TH; ++k) dp[k] = 0.0f;
        float over = 0.0f;
        const float p0 = fast_sigmoid(gains[i]);
        #pragma unroll
        for (int j = 0; j < NEV; ++j) {
            const float pj = (j == 0) ? p0 : fast_sigmoid(gains[row[j - 1]]);
            if (j >= TH - 1) over = fmaf(dp[TH - 1], pj, over);
            const int kmax = (j + 1 < TH - 1) ? (j + 1) : (TH - 1);
            #pragma unroll
            for (int k = kmax; k >= 1; --k)
                dp[k] = fmaf(pj, dp[k - 1] - dp[k], dp[k]);
            dp[0] = fmaf(-pj, dp[0], dp[0]);
        }
        local = fmaf(0.25f, p0, -over);
    }
    #pragma unroll
    for (int o = 32; o > 0; o >>= 1) local += __shfl_down(local, o, 64);
    if ((tid & 63) == 0) s_red[tid >> 6] = local;
    __syncthreads();
    if (tid == 0) {
        float s = 0.0f;
        #pragma unroll
        for (int w = 0; w < BLK / 64; ++w) s += s_red[w];
        atomicAdd(out, s);
    }
}

extern "C" void kernel_launch(void* const* d_in, const int* in_sizes, int n_in,
                              void* d_out, int out_size, void* d_ws, size_t ws_size,
                              hipStream_t stream) {
    const float* gains = (const float*)d_in[0];
    const int*   nbr   = (const int*)d_in[1];
    float*       out   = (float*)d_out;
    const int n = in_sizes[0];

    if (ws_size >= (size_t)TBL && n <= TBL) {
        unsigned char* tbl = (unsigned char*)d_ws;
        build_table_kernel<<<(TBL / 4 + 255) / 256, 256, 0, stream>>>(
            gains, (unsigned*)tbl, out, n);
        const int gridF = (n + NPB - 1) / NPB;
        pgl_fused_kernel<<<gridF, BLKF, 0, stream>>>(gains, nbr, tbl, out, n);
    } else {
        zero_out_kernel<<<1, 64, 0, stream>>>(out);
        const int grid = (n + BLK - 1) / BLK;
        pgl_direct_kernel<<<grid, BLK, 0, stream>>>(gains, nbr, out, n);
    }
}

// Round 8
// 268.985 us; speedup vs baseline: 1.4484x; 1.4484x over previous
//
#include <hip/hip_runtime.h>

constexpr int DEG = 31;        // neighbors per node
constexpr int NEV = 32;        // events per node (self + neighbors)
constexpr int TH  = 16;        // threshold: dp[0..15] + absorbing "over"
constexpr int BLK = 256;       // fallback block size
constexpr int TBL = 1 << 20;   // u8 table entries (padded >= n)

// scan kernel geometry
constexpr int CH    = 1 << 17;     // 128 KB LDS chunk
constexpr int NPASS = TBL / CH;    // 8 passes
constexpr int BLK3  = 1024;        // 16 waves, 1 node per thread
constexpr int PF    = CH / 16 / BLK3;  // vint4 loads per thread per chunk = 8

typedef int  vint4  __attribute__((ext_vector_type(4)));

__global__ void zero_out_kernel(float* out) {
    if (threadIdx.x == 0) out[0] = 0.0f;
}

__device__ __forceinline__ float fast_sigmoid(float x) {
    return 1.0f / (1.0f + __expf(-x));
}

// raw barrier: HW rendezvous WITHOUT the vmcnt(0) drain __syncthreads implies.
__device__ __forceinline__ void barrier_raw() {
    asm volatile("" ::: "memory");
    __builtin_amdgcn_s_barrier();
    asm volatile("" ::: "memory");
}

// ---- phase 1: u8 table tbl[i] = rint(sigmoid(gains[i])*255) + zero out ----
__global__ __launch_bounds__(256)
void build_table_kernel(const float* __restrict__ gains,
                        unsigned* __restrict__ tbl4,
                        float* __restrict__ out, int n) {
    const int t = blockIdx.x * 256 + threadIdx.x;
    if (t == 0) out[0] = 0.0f;
    if (t < TBL / 4) {
        unsigned w = 0;
        #pragma unroll
        for (int k = 0; k < 4; ++k) {
            const int i = 4 * t + k;
            const float p = (i < n) ? fast_sigmoid(gains[i]) : 0.0f;
            const unsigned b = __float2uint_rn(p * 255.0f);
            w |= (b & 0xFFu) << (8 * k);
        }
        tbl4[t] = w;
    }
}

// Poisson-binomial DP from packed u8 probability bytes (original j-order ->
// bit-identical per-node result vs all previous passing kernels).
__device__ __forceinline__ float node_dp(float g, const unsigned w[8]) {
    const float p0 = fast_sigmoid(g);
    float dp[TH];
    dp[0] = 1.0f;
    #pragma unroll
    for (int k = 1; k < TH; ++k) dp[k] = 0.0f;
    float over = 0.0f;
    #pragma unroll
    for (int j = 0; j < NEV; ++j) {
        float pj;
        if (j == 0) {
            pj = p0;
        } else {
            const unsigned b = (w[(j - 1) >> 2] >> (((j - 1) & 3) * 8)) & 0xFFu;
            pj = (float)b * (1.0f / 255.0f);
        }
        if (j >= TH - 1) over = fmaf(dp[TH - 1], pj, over);
        const int kmax = (j + 1 < TH - 1) ? (j + 1) : (TH - 1);
        #pragma unroll
        for (int k = kmax; k >= 1; --k)
            dp[k] = fmaf(pj, dp[k - 1] - dp[k], dp[k]);
        dp[0] = fmaf(-pj, dp[0], dp[0]);
    }
    return fmaf(0.25f, p0, -over);
}

// ---- phase 2: streaming-scan gather ----
// Replaces 31M random L2 byte-requests (capped at ~13.5 TB/s line-equivalent,
// r0-r2) with STREAMING L2 reads: each block sweeps the 1 MB table through
// LDS in 8 x 128 KB chunks (977 blocks x 1 MB = 977 MB @ 34.5 TB/s ~= 28 us
// floor). r3's scan overheads removed:
//  - reg-prefetch: next chunk's loads issued before the probe phase, held in
//    flight across raw barriers (plain C++ loads -> compiler-owned waitcnts)
//  - branchless batched probes: 8 clamped ds_read_u8 back-to-back, one wait,
//    select-merge (r3's branchy probe serialized ~992 x 120cy LDS latency)
//  - 1 node/thread: 31 index regs, no AGPR churn, no spill
__global__ __launch_bounds__(BLK3, 4)
void pgl3_kernel(const float* __restrict__ gains,
                 const int*   __restrict__ nbr,
                 const unsigned char* __restrict__ tbl,
                 float*       __restrict__ out, int n) {
    __shared__ __align__(16) unsigned char smem[CH];   // 128 KB multi-purpose

    const int tid        = threadIdx.x;
    const int blockStart = blockIdx.x * BLK3;
    const int rows       = min(BLK3, n - blockStart);

    // ---- prefetch chunk 0 immediately (in flight during the bounce) ----
    vint4 pf[PF];
    {
        const vint4* src = (const vint4*)tbl;
        #pragma unroll
        for (int q = 0; q < PF; ++q) pf[q] = src[q * BLK3 + tid];
    }

    // ---- bounce neighbor rows through LDS into registers (124 KB fits) ----
    unsigned idx[DEG];
    {
        const int elems = rows * DEG;
        const size_t base = (size_t)blockStart * DEG;
        const vint4* nb4 = (const vint4*)(nbr + base);   // 1024*31*4 % 16 == 0
        vint4* s4 = (vint4*)smem;
        const int nvec = elems >> 2;
        for (int v = tid; v < nvec; v += BLK3)
            s4[v] = __builtin_nontemporal_load(nb4 + v);
        for (int e = (nvec << 2) + tid; e < elems; e += BLK3)
            ((int*)smem)[e] = __builtin_nontemporal_load(nbr + base + e);
        __syncthreads();
        if (tid < rows) {
            const int* row = (const int*)smem + tid * DEG;
            #pragma unroll
            for (int j = 0; j < DEG; ++j) idx[j] = (unsigned)row[j];
        } else {
            #pragma unroll
            for (int j = 0; j < DEG; ++j) idx[j] = 0u;
        }
    }

    unsigned w[8];
    #pragma unroll
    for (int q = 0; q < 8; ++q) w[q] = 0u;

    // ---- pass loop ----
    #pragma unroll 1
    for (int c = 0; c < NPASS; ++c) {
        barrier_raw();                       // (A) prev probe reads consumed
        {
            // write chunk c from regs (compiler waits vmcnt for pf deps)
            vint4* dst = (vint4*)smem;
            #pragma unroll
            for (int q = 0; q < PF; ++q) dst[q * BLK3 + tid] = pf[q];
            // issue prefetch of chunk c+1 (in flight across barrier + probe)
            if (c + 1 < NPASS) {
                const vint4* src = (const vint4*)(tbl + (size_t)(c + 1) * CH);
                #pragma unroll
                for (int q = 0; q < PF; ++q) pf[q] = src[q * BLK3 + tid];
            }
        }
        asm volatile("s_waitcnt lgkmcnt(0)" ::: "memory");   // my ds_writes done
        barrier_raw();                       // (B) chunk c visible to all

        // ---- branchless batched probe: 31 checks in batches of 8 ----
        const unsigned cbase = (unsigned)c * (unsigned)CH;
        #pragma unroll
        for (int jb = 0; jb < DEG; jb += 8) {
            const int m = (jb + 8 <= DEG) ? 8 : (DEG - jb);
            unsigned r[8], b[8];
            #pragma unroll
            for (int u = 0; u < m; ++u) {
                r[u] = idx[jb + u] - cbase;          // unsigned wrap = chunk test
                const unsigned a = (r[u] < (unsigned)CH) ? r[u] : 0u;
                b[u] = (unsigned)smem[a];            // always-read (no branch)
            }
            #pragma unroll
            for (int u = 0; u < m; ++u) {
                const int j = jb + u;
                w[j >> 2] |= (r[u] < (unsigned)CH)
                                 ? ((b[u] & 0xFFu) << ((j & 3) * 8)) : 0u;
            }
        }
    }

    // ---- DP + reduction ----
    float local = 0.0f;
    const int node = blockStart + tid;
    if (node < n)
        local = node_dp(__builtin_nontemporal_load(gains + node), w);

    #pragma unroll
    for (int o = 32; o > 0; o >>= 1) local += __shfl_down(local, o, 64);
    __syncthreads();                         // full drain fine at the end
    if ((tid & 63) == 0) ((float*)smem)[tid >> 6] = local;
    __syncthreads();
    if (tid == 0) {
        float s = 0.0f;
        #pragma unroll
        for (int wv = 0; wv < BLK3 / 64; ++wv) s += ((float*)smem)[wv];
        atomicAdd(out, s);
    }
}

// ---- fallback (ws too small): f32 direct gather ----
__global__ __launch_bounds__(BLK)
void pgl_direct_kernel(const float* __restrict__ gains,
                       const int*   __restrict__ nbr,
                       float*       __restrict__ out, int n) {
    __shared__ int s_idx[BLK * DEG];
    __shared__ float s_red[BLK / 64];
    const int tid = threadIdx.x;
    const int blockStart = blockIdx.x * BLK;
    const int rows  = min(BLK, n - blockStart);
    const int elems = rows * DEG;
    const int base  = blockStart * DEG;
    const int4* nb4 = (const int4*)(nbr + base);
    int4* s4 = (int4*)s_idx;
    const int nvec = elems >> 2;
    for (int v = tid; v < nvec; v += BLK) s4[v] = nb4[v];
    for (int e = (nvec << 2) + tid; e < elems; e += BLK) s_idx[e] = nbr[base + e];
    __syncthreads();
    float local = 0.0f;
    const int i = blockStart + tid;
    if (i < n) {
        const int* row = s_idx + tid * DEG;
        float dp[TH];
        dp[0] = 1.0f;
        #pragma unroll
        for (int k = 1; k < TH; ++k) dp[k] = 0.0f;
        float over = 0.0f;
        const float p0 = fast_sigmoid(gains[i]);
        #pragma unroll
        for (int j = 0; j < NEV; ++j) {
            const float pj = (j == 0) ? p0 : fast_sigmoid(gains[row[j - 1]]);
            if (j >= TH - 1) over = fmaf(dp[TH - 1], pj, over);
            const int kmax = (j + 1 < TH - 1) ? (j + 1) : (TH - 1);
            #pragma unroll
            for (int k = kmax; k >= 1; --k)
                dp[k] = fmaf(pj, dp[k - 1] - dp[k], dp[k]);
            dp[0] = fmaf(-pj, dp[0], dp[0]);
        }
        local = fmaf(0.25f, p0, -over);
    }
    #pragma unroll
    for (int o = 32; o > 0; o >>= 1) local += __shfl_down(local, o, 64);
    if ((tid & 63) == 0) s_red[tid >> 6] = local;
    __syncthreads();
    if (tid == 0) {
        float s = 0.0f;
        #pragma unroll
        for (int w = 0; w < BLK / 64; ++w) s += s_red[w];
        atomicAdd(out, s);
    }
}

extern "C" void kernel_launch(void* const* d_in, const int* in_sizes, int n_in,
                              void* d_out, int out_size, void* d_ws, size_t ws_size,
                              hipStream_t stream) {
    const float* gains = (const float*)d_in[0];
    const int*   nbr   = (const int*)d_in[1];
    float*       out   = (float*)d_out;
    const int n = in_sizes[0];

    if (ws_size >= (size_t)TBL && n <= TBL) {
        unsigned char* tbl = (unsigned char*)d_ws;
        build_table_kernel<<<(TBL / 4 + 255) / 256, 256, 0, stream>>>(
            gains, (unsigned*)tbl, out, n);
        const int grid3 = (n + BLK3 - 1) / BLK3;
        pgl3_kernel<<<grid3, BLK3, 0, stream>>>(gains, nbr, tbl, out, n);
    } else {
        zero_out_kernel<<<1, 64, 0, stream>>>(out);
        const int grid = (n + BLK - 1) / BLK;
        pgl_direct_kernel<<<grid, BLK, 0, stream>>>(gains, nbr, out, n);
    }
}